// Round 13
// baseline (219.000 us; speedup 1.0000x reference)
//
#include <hip/hip_runtime.h>
#include <hip/hip_fp16.h>
#include <string.h>

#define DIM 256

typedef __attribute__((ext_vector_type(2))) _Float16 half2v;

#if defined(__has_builtin)
#if __has_builtin(__builtin_amdgcn_fdot2)
#define HAVE_FDOT2 1
#endif
#endif

// ---------- merged fp32 -> fp16 pair-interleave compression (node + rel) -------
// Row layout out: pair j at halves [2j,2j+1] = (in[j], in[j+128]).
// 32 threads per row; thread q reads float4 from real half [4q..4q+4) and
// float4 from imag half [128+4q..), writes one int4 (4 half2 pairs).
// Rows [0, n_node) from node table, rows [n_node, n_total) from rel table.
__global__ __launch_bounds__(256) void compress_f16i_kernel(
    const float* __restrict__ node, const float* __restrict__ rel,
    int4* __restrict__ out, int n_node, int n_total)
{
    int i = blockIdx.x * blockDim.x + threadIdx.x;
    int row = i >> 5;
    int q   = i & 31;
    if (row >= n_total) return;

    const float* base = (row < n_node)
        ? (node + (size_t)row * DIM)
        : (rel + (size_t)(row - n_node) * DIM);

    float4 a = *((const float4*)base + q);
    float4 b = *((const float4*)(base + 128) + q);

    __half2 p0 = __float22half2_rn(make_float2(a.x, b.x));
    __half2 p1 = __float22half2_rn(make_float2(a.y, b.y));
    __half2 p2 = __float22half2_rn(make_float2(a.z, b.z));
    __half2 p3 = __float22half2_rn(make_float2(a.w, b.w));

    int4 o;
    memcpy(&o.x, &p0, 4);
    memcpy(&o.y, &p1, 4);
    memcpy(&o.z, &p2, 4);
    memcpy(&o.w, &p3, 4);
    out[(size_t)row * 32 + q] = o;
}

// ---------- per-pair score term ------------------------------------------------
__device__ __forceinline__ float pair_term(int h32, int t32, int r32, float acc)
{
    unsigned tu = (unsigned)t32;
    unsigned tsw = (tu >> 16) | ((tu << 16) ^ 0x80000000u);  // (it, -rt)

    half2v h2, t2, r2, ts2;
    memcpy(&h2, &h32, 4);
    memcpy(&t2, &t32, 4);
    memcpy(&r2, &r32, 4);
    memcpy(&ts2, &tsw, 4);

#ifdef HAVE_FDOT2
    float u = __builtin_amdgcn_fdot2(r2, t2, 0.0f, false);
    float v = __builtin_amdgcn_fdot2(r2, ts2, 0.0f, false);
#else
    float rr = (float)r2.x, ir = (float)r2.y;
    float rt = (float)t2.x, it = (float)t2.y;
    float u = rr * rt + ir * it;
    float v = rr * it - ir * rt;
    (void)ts2;
#endif
    float rh = (float)h2.x;
    float ih = (float)h2.y;
    acc = fmaf(rh, u, acc);
    acc = fmaf(ih, v, acc);
    return acc;
}

// ---------- score kernel: 4 edges per 32-lane group (4x memory-level par.) -----
// Group g handles edges g + k*quarter, k=0..3. All 12 row-gathers issued
// before any compute.
__global__ __launch_bounds__(256) void complex_score_f16i4_kernel(
    const __half* __restrict__ node,
    const __half* __restrict__ rel,
    const int* __restrict__ src,
    const int* __restrict__ dst,
    const int* __restrict__ rid,
    float* __restrict__ out,
    int n_edges, int quarter)
{
    const int tid  = blockIdx.x * blockDim.x + threadIdx.x;
    const int g    = tid >> 5;
    const int lane = tid & 31;
    if (g >= quarter) return;

    int e[4];
    bool have[4];
    #pragma unroll
    for (int k = 0; k < 4; ++k) {
        e[k] = g + k * quarter;
        have[k] = (e[k] < n_edges);
    }

    int s[4], d[4], r[4];
    #pragma unroll
    for (int k = 0; k < 4; ++k) {
        int ek = have[k] ? e[k] : 0;
        s[k] = src[ek];
        d[k] = dst[ek];
        r[k] = rid[ek];
    }

    const int4* np = (const int4*)node;
    const int4* rp = (const int4*)rel;

    // issue all twelve row loads before any compute
    int4 hv[4], tv[4], vv[4];
    #pragma unroll
    for (int k = 0; k < 4; ++k) {
        hv[k] = np[(size_t)s[k] * 32 + lane];
        tv[k] = np[(size_t)d[k] * 32 + lane];
        vv[k] = rp[(size_t)r[k] * 32 + lane];
    }

    float acc[4];
    #pragma unroll
    for (int k = 0; k < 4; ++k) {
        float a = 0.0f;
        a = pair_term(hv[k].x, tv[k].x, vv[k].x, a);
        a = pair_term(hv[k].y, tv[k].y, vv[k].y, a);
        a = pair_term(hv[k].z, tv[k].z, vv[k].z, a);
        a = pair_term(hv[k].w, tv[k].w, vv[k].w, a);
        acc[k] = a;
    }

    #pragma unroll
    for (int off = 16; off > 0; off >>= 1) {
        #pragma unroll
        for (int k = 0; k < 4; ++k)
            acc[k] += __shfl_xor(acc[k], off);
    }

    if (lane == 0) {
        #pragma unroll
        for (int k = 0; k < 4; ++k)
            if (have[k]) out[e[k]] = acc[k];
    }
}

// ---------- fallback: direct fp32 path (if ws is too small) --------------------
__global__ __launch_bounds__(256) void complex_score_f32_kernel(
    const float* __restrict__ node_emb,
    const float* __restrict__ rel_emb,
    const int* __restrict__ src,
    const int* __restrict__ dst,
    const int* __restrict__ rel_id,
    float* __restrict__ out,
    int n_edges)
{
    const int tid  = blockIdx.x * blockDim.x + threadIdx.x;
    const int edge = tid >> 5;
    const int lane = tid & 31;
    if (edge >= n_edges) return;

    const int s = src[edge];
    const int d = dst[edge];
    const int r = rel_id[edge];

    const float4* hp = (const float4*)(node_emb + (size_t)s * DIM);
    const float4* tp = (const float4*)(node_emb + (size_t)d * DIM);
    const float4* rp = (const float4*)(rel_emb  + (size_t)r * DIM);

    float4 rh = hp[lane];
    float4 ih = hp[lane + 32];
    float4 rt = tp[lane];
    float4 it = tp[lane + 32];
    float4 rr = rp[lane];
    float4 ir = rp[lane + 32];

    float a0 = rr.x * (rh.x * rt.x + ih.x * it.x) + ir.x * (rh.x * it.x - ih.x * rt.x);
    float a1 = rr.y * (rh.y * rt.y + ih.y * it.y) + ir.y * (rh.y * it.y - ih.y * rt.y);
    float a2 = rr.z * (rh.z * rt.z + ih.z * it.z) + ir.z * (rh.z * it.z - ih.z * rt.z);
    float a3 = rr.w * (rh.w * rt.w + ih.w * it.w) + ir.w * (rh.w * it.w - ih.w * rt.w);
    float acc = (a0 + a1) + (a2 + a3);

    #pragma unroll
    for (int off = 16; off > 0; off >>= 1)
        acc += __shfl_xor(acc, off, 32);

    if (lane == 0)
        out[edge] = acc;
}

extern "C" void kernel_launch(void* const* d_in, const int* in_sizes, int n_in,
                              void* d_out, int out_size, void* d_ws, size_t ws_size,
                              hipStream_t stream) {
    const float* node_emb = (const float*)d_in[0];
    const float* rel_emb  = (const float*)d_in[1];
    const int*   src      = (const int*)d_in[2];
    const int*   dst      = (const int*)d_in[3];
    const int*   rel_id   = (const int*)d_in[4];
    float* out = (float*)d_out;

    const int n_edges = in_sizes[2];            // 400000
    const int n_nodes = in_sizes[0] / DIM;      // 100000
    const int n_rels  = in_sizes[1] / DIM;      // 1000

    const size_t f16_bytes = ((size_t)n_nodes + (size_t)n_rels) * DIM * 2;
    const int tpb = 256;

    if (ws_size >= f16_bytes) {
        __half* node_f16 = (__half*)d_ws;
        __half* rel_f16  = node_f16 + (size_t)n_nodes * DIM;

        const int n_total_rows = n_nodes + n_rels;
        const long long comp_threads = (long long)n_total_rows * 32;
        compress_f16i_kernel<<<(int)((comp_threads + tpb - 1) / tpb), tpb, 0, stream>>>(
            node_emb, rel_emb, (int4*)d_ws, n_nodes, n_total_rows);

        const int quarter = (n_edges + 3) / 4;
        const long long score_threads = (long long)quarter * 32;
        complex_score_f16i4_kernel<<<(int)((score_threads + tpb - 1) / tpb), tpb, 0, stream>>>(
            node_f16, rel_f16, src, dst, rel_id, out, n_edges, quarter);
    } else {
        const long long total_threads = (long long)n_edges * 32;
        complex_score_f32_kernel<<<(int)((total_threads + tpb - 1) / tpb), tpb, 0, stream>>>(
            node_emb, rel_emb, src, dst, rel_id, out, n_edges);
    }
}